// Round 1
// baseline (705.134 us; speedup 1.0000x reference)
//
#include <hip/hip_runtime.h>
#include <math.h>

#define NATOM 32768
#define NMOL 8
#define PERM 4096
#define LOG2PERM 12
#define NPAIR 2097152
#define NKK 625           // 25x25 k-grid, invalid entries get coef=0

#define KE_C 14.3996f
#define ALPHA_C 0.3f
#define CUTOFF_C 6.0f
#define SQRT_ALPHA_C 0.5477225575051661f   // sqrt(0.3)
#define ACONST_C 0.6180387232371366f       // 2*sqrt(alpha/pi)
#define SELF_C 0.3090193616185683f         // sqrt(alpha/pi)
#define TWO_PI_C 6.283185307179586f

// persistent device state (zeroed per launch as needed)
__device__ float4 g_X[NATOM];      // x,y,z,q
__device__ float4 g_V[NATOM];      // tangent direction (film*F), w=film
__device__ float4 g_G[NATOM];      // dE/dX
__device__ float4 g_HV[NATOM];     // H*V
__device__ float4 g_kvc[NMOL*NKK]; // kvx,kvy,kvz,coef
__device__ float2 g_S[NMOL*NKK];   // S_re,S_im
__device__ float2 g_Sd[NMOL*NKK];  // Sdot_re,Sdot_im
__device__ float g_recipM[NMOL][9];
__device__ float g_vbox[NMOL];
__device__ float g_self[NMOL];
__device__ float g_yreal[NMOL];
__device__ float g_yborn[NMOL];
__device__ float g_yrecip[NMOL];
__device__ float g_Fm[NMOL][3];
__device__ float g_norm2[NMOL];
__device__ float g_D, g_Dd, g_C2, g_FRC;

__device__ __forceinline__ float waveReduce(float v){
#pragma unroll
    for (int off = 32; off > 0; off >>= 1) v += __shfl_down(v, off, 64);
    return v;
}

__global__ void k_zero(){
    int id = blockIdx.x*blockDim.x + threadIdx.x;
    if (id < NATOM){
        g_G[id]  = make_float4(0.f,0.f,0.f,0.f);
        g_HV[id] = make_float4(0.f,0.f,0.f,0.f);
    }
    if (id < NMOL*NKK){
        g_S[id]  = make_float2(0.f,0.f);
        g_Sd[id] = make_float2(0.f,0.f);
    }
    if (id < NMOL){
        g_self[id] = 0.f; g_yreal[id] = 0.f; g_yborn[id] = 0.f;
    }
    if (id == 0){ g_D = 0.f; g_Dd = 0.f; }
}

__global__ void k_prep(const float* cell){
    int m = threadIdx.x;
    if (m < NMOL){
        const float* c = cell + 9*m;
        float a=c[0],b=c[1],cc=c[2],d=c[3],e=c[4],f=c[5],g=c[6],h=c[7],i=c[8];
        float det = a*(e*i - f*h) - b*(d*i - f*g) + cc*(d*h - e*g);
        float inv = 1.f/det;
        float i00=(e*i-f*h)*inv,  i01=(cc*h-b*i)*inv, i02=(b*f-cc*e)*inv;
        float i10=(f*g-d*i)*inv,  i11=(a*i-cc*g)*inv, i12=(cc*d-a*f)*inv;
        float i20=(d*h-e*g)*inv,  i21=(b*g-a*h)*inv,  i22=(a*e-b*d)*inv;
        // recipM[d][e] = 2*pi*inv[e][d]  (swapaxes of inverse)
        g_recipM[m][0]=TWO_PI_C*i00; g_recipM[m][1]=TWO_PI_C*i10; g_recipM[m][2]=TWO_PI_C*i20;
        g_recipM[m][3]=TWO_PI_C*i01; g_recipM[m][4]=TWO_PI_C*i11; g_recipM[m][5]=TWO_PI_C*i21;
        g_recipM[m][6]=TWO_PI_C*i02; g_recipM[m][7]=TWO_PI_C*i12; g_recipM[m][8]=TWO_PI_C*i22;
        g_vbox[m] = fabsf(det);
    }
    __syncthreads();
    if (threadIdx.x == 0){
        float c2 = 0.f;
        for (int mm = 0; mm < NMOL; ++mm) c2 += TWO_PI_C/g_vbox[mm];
        g_C2 = c2;
        g_FRC = (float)(erfc(sqrt(0.3)*6.0)/6.0);
    }
}

__global__ void k_kvec(){
    int id = blockIdx.x*blockDim.x + threadIdx.x;
    if (id >= NMOL*NKK) return;
    int m = id / NKK;
    int kk = id % NKK;
    int ix = kk / 25, iy = kk % 25;
    float kx = (ix <= 12) ? (float)ix : (float)(-(ix-12));
    float ky = (iy <= 12) ? (float)iy : (float)(-(iy-12));
    float nrm = kx*kx + ky*ky;
    float kvx = kx*g_recipM[m][0] + ky*g_recipM[m][3];
    float kvy = kx*g_recipM[m][1] + ky*g_recipM[m][4];
    float kvz = kx*g_recipM[m][2] + ky*g_recipM[m][5];
    float coef = 0.f;
    if (nrm != 0.f && nrm <= 146.f){
        float ksq = kvx*kvx + kvy*kvy + kvz*kvz;
        coef = (TWO_PI_C/g_vbox[m]) * expf(-0.25f*ksq/ALPHA_C) / ksq;
    }
    g_kvc[id] = make_float4(kvx, kvy, kvz, coef);
}

__global__ void k_shift(const float* q, const float* R, const float* shift, const int* is_film){
    int n = blockIdx.x*blockDim.x + threadIdx.x;
    int m = n >> LOG2PERM;
    int film = is_film[n];
    float qn = q[n];
    float x = R[3*n+0], y = R[3*n+1], z = R[3*n+2];
    if (film){ x += shift[3*m+0]; y += shift[3*m+1]; z += shift[3*m+2]; }
    g_X[n] = make_float4(x, y, z, qn);
    float vD = waveReduce(qn*z);
    float vS = waveReduce(qn*qn);
    __shared__ float red[8];
    int lane = threadIdx.x & 63, w = threadIdx.x >> 6;
    if (!lane){ red[w] = vD; red[4+w] = vS; }
    __syncthreads();
    if (threadIdx.x == 0){
        atomicAdd(&g_D, red[0]+red[1]+red[2]+red[3]);
        atomicAdd(&g_self[m], red[4]+red[5]+red[6]+red[7]);
    }
}

template<int DOT>
__global__ void k_sfac(){
    int bid = blockIdx.x;
    int m = bid / NKK;
    float4 kvc = g_kvc[bid];
    if (kvc.w == 0.f) return;   // uniform per block
    float sre = 0.f, sim = 0.f;
    for (int a = threadIdx.x; a < PERM; a += blockDim.x){
        int n = (m << LOG2PERM) + a;
        float4 x = g_X[n];
        float th = kvc.x*x.x + kvc.y*x.y + kvc.z*x.z;
        float s, c;
        sincosf(th, &s, &c);
        if (DOT){
            float4 v = g_V[n];
            float thd = kvc.x*v.x + kvc.y*v.y + kvc.z*v.z;
            sre -= x.w*s*thd;
            sim += x.w*c*thd;
        } else {
            sre += x.w*c;
            sim += x.w*s;
        }
    }
    sre = waveReduce(sre); sim = waveReduce(sim);
    __shared__ float red[8];
    int lane = threadIdx.x & 63, w = threadIdx.x >> 6;
    if (!lane){ red[w] = sre; red[4+w] = sim; }
    __syncthreads();
    if (threadIdx.x == 0){
        float2 o = make_float2(red[0]+red[1]+red[2]+red[3], red[4]+red[5]+red[6]+red[7]);
        if (DOT) g_Sd[bid] = o; else g_S[bid] = o;
    }
}

__global__ void k_recip_energy(){
    int m = blockIdx.x;
    float acc = 0.f;
    for (int kk = threadIdx.x; kk < NKK; kk += blockDim.x){
        float4 kvc = g_kvc[m*NKK + kk];
        float2 S = g_S[m*NKK + kk];
        acc += kvc.w*(S.x*S.x + S.y*S.y);
    }
    acc = waveReduce(acc);
    __shared__ float red[4];
    int lane = threadIdx.x & 63, w = threadIdx.x >> 6;
    if (!lane) red[w] = acc;
    __syncthreads();
    if (threadIdx.x == 0){
        float yew = red[0]+red[1]+red[2]+red[3];
        float D = g_D;
        float yslab = KE_C*(TWO_PI_C/g_vbox[m])*D*D;
        g_yrecip[m] = KE_C*(yew - SELF_C*g_self[m]) + yslab;
    }
}

template<int PASS>
__global__ void k_pairs(const int* idx_i, const int* idx_j,
                        const float* r0_ij, const float* n_ij,
                        const float* offsets){
    __shared__ float sreal[NMOL], sborn[NMOL];
    int p = blockIdx.x*blockDim.x + threadIdx.x;
    if (PASS == 0){
        if (threadIdx.x < NMOL){ sreal[threadIdx.x] = 0.f; sborn[threadIdx.x] = 0.f; }
        __syncthreads();
    }
    int i = idx_i[p], j = idx_j[p];
    float4 xi = g_X[i], xj = g_X[j];
    float rx = xj.x - xi.x + offsets[3*p+0];
    float ry = xj.y - xi.y + offsets[3*p+1];
    float rz = xj.z - xi.z + offsets[3*p+2];
    float d2 = rx*rx + ry*ry + rz*rz;
    float d = sqrtf(d2);
    if (d < CUTOFF_C){
        float inv_d = 1.f/d;
        float qq = xi.w*xj.w;
        float nij = n_ij[p];
        float r0 = r0_ij[p];
        float B = fabsf(qq)*powf(r0, nij - 1.f)/nij;
        float er = erfcf(SQRT_ALPHA_C*d);
        float expt = expf(-ALPHA_C*d2);
        float dmn = powf(d, -nij);                       // d^-n
        float fp = -ACONST_C*expt*inv_d - er*inv_d*inv_d; // f'(d)
        float Up = 0.5f*KE_C*(qq*fp - B*nij*dmn*inv_d);  // U'(d)
        if (PASS == 0){
            float pot  = qq*(er*inv_d - g_FRC);
            float born = B*(dmn - powf(CUTOFF_C, -nij));
            int mm = i >> LOG2PERM;
            atomicAdd(&sreal[mm], pot);
            atomicAdd(&sborn[mm], born);
            float sc = Up*inv_d;
            float gx = sc*rx, gy = sc*ry, gz = sc*rz;
            atomicAdd(&g_G[j].x,  gx); atomicAdd(&g_G[j].y,  gy); atomicAdd(&g_G[j].z,  gz);
            atomicAdd(&g_G[i].x, -gx); atomicAdd(&g_G[i].y, -gy); atomicAdd(&g_G[i].z, -gz);
        } else {
            float fpp = ACONST_C*expt*(2.f*ALPHA_C + 2.f*inv_d*inv_d) + 2.f*er*inv_d*inv_d*inv_d;
            float Upp = 0.5f*KE_C*(qq*fpp + B*nij*(nij+1.f)*dmn*inv_d*inv_d);
            float4 vi = g_V[i], vj = g_V[j];
            float dvx = vj.x - vi.x, dvy = vj.y - vi.y, dvz = vj.z - vi.z;
            float ddot = (rx*dvx + ry*dvy + rz*dvz)*inv_d;
            float ui = Up*inv_d;
            float c1 = (Upp - ui)*ddot*inv_d;
            float gx = c1*rx + ui*dvx;
            float gy = c1*ry + ui*dvy;
            float gz = c1*rz + ui*dvz;
            atomicAdd(&g_HV[j].x,  gx); atomicAdd(&g_HV[j].y,  gy); atomicAdd(&g_HV[j].z,  gz);
            atomicAdd(&g_HV[i].x, -gx); atomicAdd(&g_HV[i].y, -gy); atomicAdd(&g_HV[i].z, -gz);
        }
    }
    if (PASS == 0){
        __syncthreads();
        if (threadIdx.x < NMOL){
            atomicAdd(&g_yreal[threadIdx.x], sreal[threadIdx.x]);
            atomicAdd(&g_yborn[threadIdx.x], sborn[threadIdx.x]);
        }
    }
}

template<int PASS>
__global__ void k_recip_grad(){
    int n = blockIdx.x*blockDim.x + threadIdx.x;
    int m = n >> LOG2PERM;
    float4 x4 = g_X[n];
    float4 v4 = make_float4(0.f,0.f,0.f,0.f);
    if (PASS) v4 = g_V[n];
    float ax = 0.f, ay = 0.f, az = 0.f;
    const float4* kvb = g_kvc + m*NKK;
    const float2* Sb  = g_S   + m*NKK;
    const float2* Sdb = g_Sd  + m*NKK;
    for (int kk = 0; kk < NKK; ++kk){
        float4 kvc = kvb[kk];
        if (kvc.w == 0.f) continue;
        float th = kvc.x*x4.x + kvc.y*x4.y + kvc.z*x4.z;
        float s, c;
        sincosf(th, &s, &c);
        float2 S = Sb[kk];
        float t;
        if (PASS == 0){
            t = kvc.w*(S.y*c - S.x*s);
        } else {
            float2 Sd = Sdb[kk];
            float thd = kvc.x*v4.x + kvc.y*v4.y + kvc.z*v4.z;
            t = kvc.w*(Sd.y*c - Sd.x*s - (S.y*s + S.x*c)*thd);
        }
        ax += t*kvc.x; ay += t*kvc.y; az += t*kvc.z;
    }
    float sc = 2.f*KE_C*x4.w;
    float slab = 2.f*KE_C*g_C2*x4.w*(PASS ? g_Dd : g_D);
    float4* T = PASS ? g_HV : g_G;
    float4 t0 = T[n];
    t0.x += sc*ax;
    t0.y += sc*ay;
    t0.z += sc*az + slab;
    T[n] = t0;
}

__global__ void k_reduce_F(const int* is_film){
    int m = blockIdx.x;
    float fx = 0.f, fy = 0.f, fz = 0.f;
    for (int a = threadIdx.x; a < PERM; a += blockDim.x){
        int n = (m << LOG2PERM) + a;
        float film = (float)is_film[n];
        float4 g = g_G[n];
        fx -= film*g.x; fy -= film*g.y; fz -= film*g.z;
    }
    fx = waveReduce(fx); fy = waveReduce(fy); fz = waveReduce(fz);
    __shared__ float red[12];
    int lane = threadIdx.x & 63, w = threadIdx.x >> 6;
    if (!lane){ red[w] = fx; red[4+w] = fy; red[8+w] = fz; }
    __syncthreads();
    if (threadIdx.x == 0){
        float FX = red[0]+red[1]+red[2]+red[3];
        float FY = red[4]+red[5]+red[6]+red[7];
        float FZ = red[8]+red[9]+red[10]+red[11];
        g_Fm[m][0] = FX; g_Fm[m][1] = FY; g_Fm[m][2] = FZ;
        g_norm2[m] = FX*FX + FY*FY + FZ*FZ;
    }
}

__global__ void k_setV(const int* is_film){
    int n = blockIdx.x*blockDim.x + threadIdx.x;
    int m = n >> LOG2PERM;
    float film = (float)is_film[n];
    float vx = film*g_Fm[m][0], vy = film*g_Fm[m][1], vz = film*g_Fm[m][2];
    g_V[n] = make_float4(vx, vy, vz, film);
    float contrib = waveReduce(g_X[n].w * vz);
    __shared__ float red[4];
    int lane = threadIdx.x & 63, w = threadIdx.x >> 6;
    if (!lane) red[w] = contrib;
    __syncthreads();
    if (threadIdx.x == 0) atomicAdd(&g_Dd, red[0]+red[1]+red[2]+red[3]);
}

__global__ void k_final(const int* is_film, float* out){
    int m = blockIdx.x;
    float ax = 0.f, ay = 0.f, az = 0.f;
    for (int a = threadIdx.x; a < PERM; a += blockDim.x){
        int n = (m << LOG2PERM) + a;
        float film = (float)is_film[n];
        float4 hv = g_HV[n];
        ax += film*hv.x; ay += film*hv.y; az += film*hv.z;
    }
    ax = waveReduce(ax); ay = waveReduce(ay); az = waveReduce(az);
    __shared__ float red[12];
    int lane = threadIdx.x & 63, w = threadIdx.x >> 6;
    if (!lane){ red[w] = ax; red[4+w] = ay; red[8+w] = az; }
    __syncthreads();
    if (threadIdx.x == 0){
        float AX = red[0]+red[1]+red[2]+red[3];
        float AY = red[4]+red[5]+red[6]+red[7];
        float AZ = red[8]+red[9]+red[10]+red[11];
        out[32 + 3*m + 0] = -2.f*AX;
        out[32 + 3*m + 1] = -2.f*AY;
        out[32 + 3*m + 2] = -2.f*AZ;
        float yr = 0.5f*KE_C*g_yreal[m];
        float yb = 0.5f*KE_C*g_yborn[m];
        float yc = yr + g_yrecip[m];
        out[0  + m] = yc + yb;
        out[8  + m] = yc;
        out[16 + m] = yb;
        out[24 + m] = g_norm2[m];
    }
}

extern "C" void kernel_launch(void* const* d_in, const int* in_sizes, int n_in,
                              void* d_out, int out_size, void* d_ws, size_t ws_size,
                              hipStream_t stream){
    const float* q       = (const float*)d_in[0];
    const float* R       = (const float*)d_in[1];
    const float* shift   = (const float*)d_in[2];
    const float* cell    = (const float*)d_in[3];
    const float* offsets = (const float*)d_in[4];
    const float* r0_ij   = (const float*)d_in[5];
    const float* n_ij    = (const float*)d_in[6];
    const int*   idx_i   = (const int*)d_in[7];
    const int*   idx_j   = (const int*)d_in[8];
    const int*   is_film = (const int*)d_in[10];
    float* out = (float*)d_out;

    k_zero<<<dim3(128), dim3(256), 0, stream>>>();
    k_prep<<<dim3(1), dim3(64), 0, stream>>>(cell);
    k_kvec<<<dim3((NMOL*NKK + 255)/256), dim3(256), 0, stream>>>();
    k_shift<<<dim3(NATOM/256), dim3(256), 0, stream>>>(q, R, shift, is_film);
    k_sfac<0><<<dim3(NMOL*NKK), dim3(256), 0, stream>>>();
    k_recip_energy<<<dim3(NMOL), dim3(256), 0, stream>>>();
    k_pairs<0><<<dim3(NPAIR/256), dim3(256), 0, stream>>>(idx_i, idx_j, r0_ij, n_ij, offsets);
    k_recip_grad<0><<<dim3(NATOM/256), dim3(256), 0, stream>>>();
    k_reduce_F<<<dim3(NMOL), dim3(256), 0, stream>>>(is_film);
    k_setV<<<dim3(NATOM/256), dim3(256), 0, stream>>>(is_film);
    k_sfac<1><<<dim3(NMOL*NKK), dim3(256), 0, stream>>>();
    k_pairs<1><<<dim3(NPAIR/256), dim3(256), 0, stream>>>(idx_i, idx_j, r0_ij, n_ij, offsets);
    k_recip_grad<1><<<dim3(NATOM/256), dim3(256), 0, stream>>>();
    k_final<<<dim3(NMOL), dim3(256), 0, stream>>>(is_film, out);
}

// Round 2
// 541.123 us; speedup vs baseline: 1.3031x; 1.3031x over previous
//
#include <hip/hip_runtime.h>
#include <math.h>

#define NATOM 32768
#define NMOL 8
#define PERM 4096
#define LOG2PERM 12
#define NPAIR 2097152
#define NKK 625           // 25x25 k-grid, invalid entries get coef=0
#define CAPREC 524288     // capacity for filtered pairs (~210k expected)

#define KE_C 14.3996f
#define ALPHA_C 0.3f
#define CUTOFF_C 6.0f
#define SQRT_ALPHA_C 0.5477225575051661f   // sqrt(0.3)
#define ACONST_C 0.6180387232371366f       // 2*sqrt(alpha/pi)
#define SELF_C 0.3090193616185683f         // sqrt(alpha/pi)
#define TWO_PI_C 6.283185307179586f

// persistent device state (zeroed per launch as needed)
__device__ float4 g_X[NATOM];      // x,y,z,q
__device__ float4 g_V[NATOM];      // tangent direction (film*F), w=film
__device__ float4 g_G[NATOM];      // dE/dX
__device__ float4 g_HV[NATOM];     // H*V
__device__ float4 g_kvc[NMOL*NKK]; // kvx,kvy,kvz,coef
__device__ float2 g_S[NMOL*NKK];   // S_re,S_im
__device__ float2 g_Sd[NMOL*NKK];  // Sdot_re,Sdot_im
__device__ float4 g_recA[CAPREC];  // packed ij, rx, ry, rz
__device__ float4 g_recB[CAPREC];  // r0, n, qq, d2
__device__ int   g_nrec;
__device__ float g_recipM[NMOL][9];
__device__ float g_vbox[NMOL];
__device__ float g_self[NMOL];
__device__ float g_yreal[NMOL];
__device__ float g_yborn[NMOL];
__device__ float g_yrecip[NMOL];
__device__ float g_Fm[NMOL][3];
__device__ float g_norm2[NMOL];
__device__ float g_D, g_Dd, g_C2, g_FRC;

__device__ __forceinline__ float waveReduce(float v){
#pragma unroll
    for (int off = 32; off > 0; off >>= 1) v += __shfl_down(v, off, 64);
    return v;
}

__global__ void k_zero(){
    int id = blockIdx.x*blockDim.x + threadIdx.x;
    if (id < NATOM){
        g_G[id]  = make_float4(0.f,0.f,0.f,0.f);
        g_HV[id] = make_float4(0.f,0.f,0.f,0.f);
    }
    if (id < NMOL*NKK){
        g_S[id]  = make_float2(0.f,0.f);
        g_Sd[id] = make_float2(0.f,0.f);
    }
    if (id < NMOL){
        g_self[id] = 0.f; g_yreal[id] = 0.f; g_yborn[id] = 0.f;
    }
    if (id == 0){ g_D = 0.f; g_Dd = 0.f; g_nrec = 0; }
}

__global__ void k_prep(const float* cell){
    int m = threadIdx.x;
    if (m < NMOL){
        const float* c = cell + 9*m;
        float a=c[0],b=c[1],cc=c[2],d=c[3],e=c[4],f=c[5],g=c[6],h=c[7],i=c[8];
        float det = a*(e*i - f*h) - b*(d*i - f*g) + cc*(d*h - e*g);
        float inv = 1.f/det;
        float i00=(e*i-f*h)*inv,  i01=(cc*h-b*i)*inv, i02=(b*f-cc*e)*inv;
        float i10=(f*g-d*i)*inv,  i11=(a*i-cc*g)*inv, i12=(cc*d-a*f)*inv;
        float i20=(d*h-e*g)*inv,  i21=(b*g-a*h)*inv,  i22=(a*e-b*d)*inv;
        // recipM[d][e] = 2*pi*inv[e][d]  (swapaxes of inverse)
        g_recipM[m][0]=TWO_PI_C*i00; g_recipM[m][1]=TWO_PI_C*i10; g_recipM[m][2]=TWO_PI_C*i20;
        g_recipM[m][3]=TWO_PI_C*i01; g_recipM[m][4]=TWO_PI_C*i11; g_recipM[m][5]=TWO_PI_C*i21;
        g_recipM[m][6]=TWO_PI_C*i02; g_recipM[m][7]=TWO_PI_C*i12; g_recipM[m][8]=TWO_PI_C*i22;
        g_vbox[m] = fabsf(det);
    }
    __syncthreads();
    if (threadIdx.x == 0){
        float c2 = 0.f;
        for (int mm = 0; mm < NMOL; ++mm) c2 += TWO_PI_C/g_vbox[mm];
        g_C2 = c2;
        g_FRC = (float)(erfc(sqrt(0.3)*6.0)/6.0);
    }
}

__global__ void k_kvec(){
    int id = blockIdx.x*blockDim.x + threadIdx.x;
    if (id >= NMOL*NKK) return;
    int m = id / NKK;
    int kk = id % NKK;
    int ix = kk / 25, iy = kk % 25;
    float kx = (ix <= 12) ? (float)ix : (float)(-(ix-12));
    float ky = (iy <= 12) ? (float)iy : (float)(-(iy-12));
    float nrm = kx*kx + ky*ky;
    float kvx = kx*g_recipM[m][0] + ky*g_recipM[m][3];
    float kvy = kx*g_recipM[m][1] + ky*g_recipM[m][4];
    float kvz = kx*g_recipM[m][2] + ky*g_recipM[m][5];
    float coef = 0.f;
    if (nrm != 0.f && nrm <= 146.f){
        float ksq = kvx*kvx + kvy*kvy + kvz*kvz;
        coef = (TWO_PI_C/g_vbox[m]) * expf(-0.25f*ksq/ALPHA_C) / ksq;
    }
    g_kvc[id] = make_float4(kvx, kvy, kvz, coef);
}

__global__ void k_shift(const float* q, const float* R, const float* shift, const int* is_film){
    int n = blockIdx.x*blockDim.x + threadIdx.x;
    int m = n >> LOG2PERM;
    int film = is_film[n];
    float qn = q[n];
    float x = R[3*n+0], y = R[3*n+1], z = R[3*n+2];
    if (film){ x += shift[3*m+0]; y += shift[3*m+1]; z += shift[3*m+2]; }
    g_X[n] = make_float4(x, y, z, qn);
    float vD = waveReduce(qn*z);
    float vS = waveReduce(qn*qn);
    __shared__ float red[8];
    int lane = threadIdx.x & 63, w = threadIdx.x >> 6;
    if (!lane){ red[w] = vD; red[4+w] = vS; }
    __syncthreads();
    if (threadIdx.x == 0){
        atomicAdd(&g_D, red[0]+red[1]+red[2]+red[3]);
        atomicAdd(&g_self[m], red[4]+red[5]+red[6]+red[7]);
    }
}

// filter the 2M pairs down to the ~10% inside the cutoff; store precomputed
// displacement + pair params so the pair kernels do no position gathers.
__global__ void k_filter(const int* idx_i, const int* idx_j, const float* offsets,
                         const float* r0_ij, const float* n_ij){
    __shared__ int s_red[4];
    __shared__ int s_cur;
    int tid = threadIdx.x;
    int p0 = blockIdx.x * 4096;
    int cnt = 0;
    for (int it = 0; it < 16; ++it){
        int p = p0 + it*256 + tid;
        int i = idx_i[p], j = idx_j[p];
        float4 xi = g_X[i], xj = g_X[j];
        float rx = xj.x - xi.x + offsets[3*p+0];
        float ry = xj.y - xi.y + offsets[3*p+1];
        float rz = xj.z - xi.z + offsets[3*p+2];
        float d2 = rx*rx + ry*ry + rz*rz;
        if (d2 < CUTOFF_C*CUTOFF_C) ++cnt;
    }
#pragma unroll
    for (int off = 32; off > 0; off >>= 1) cnt += __shfl_down(cnt, off, 64);
    int lane = tid & 63, w = tid >> 6;
    if (!lane) s_red[w] = cnt;
    __syncthreads();
    if (tid == 0) s_cur = atomicAdd(&g_nrec, s_red[0]+s_red[1]+s_red[2]+s_red[3]);
    __syncthreads();
    for (int it = 0; it < 16; ++it){
        int p = p0 + it*256 + tid;
        int i = idx_i[p], j = idx_j[p];
        float4 xi = g_X[i], xj = g_X[j];
        float rx = xj.x - xi.x + offsets[3*p+0];
        float ry = xj.y - xi.y + offsets[3*p+1];
        float rz = xj.z - xi.z + offsets[3*p+2];
        float d2 = rx*rx + ry*ry + rz*rz;
        if (d2 < CUTOFF_C*CUTOFF_C){
            int slot = atomicAdd(&s_cur, 1);
            if (slot < CAPREC){
                g_recA[slot] = make_float4(__uint_as_float((unsigned)i | ((unsigned)j << 16)), rx, ry, rz);
                g_recB[slot] = make_float4(r0_ij[p], n_ij[p], xi.w*xj.w, d2);
            }
        }
    }
}

template<int DOT>
__global__ void k_sfac(){
    int bid = blockIdx.x;
    int m = bid / NKK;
    float4 kvc = g_kvc[bid];
    if (kvc.w == 0.f) return;   // uniform per block
    float sre = 0.f, sim = 0.f;
    for (int a = threadIdx.x; a < PERM; a += blockDim.x){
        int n = (m << LOG2PERM) + a;
        float4 x = g_X[n];
        float th = kvc.x*x.x + kvc.y*x.y + kvc.z*x.z;
        float s, c;
        sincosf(th, &s, &c);
        if (DOT){
            float4 v = g_V[n];
            float thd = kvc.x*v.x + kvc.y*v.y + kvc.z*v.z;
            sre -= x.w*s*thd;
            sim += x.w*c*thd;
        } else {
            sre += x.w*c;
            sim += x.w*s;
        }
    }
    sre = waveReduce(sre); sim = waveReduce(sim);
    __shared__ float red[8];
    int lane = threadIdx.x & 63, w = threadIdx.x >> 6;
    if (!lane){ red[w] = sre; red[4+w] = sim; }
    __syncthreads();
    if (threadIdx.x == 0){
        float2 o = make_float2(red[0]+red[1]+red[2]+red[3], red[4]+red[5]+red[6]+red[7]);
        if (DOT) g_Sd[bid] = o; else g_S[bid] = o;
    }
}

__global__ void k_recip_energy(){
    int m = blockIdx.x;
    float acc = 0.f;
    for (int kk = threadIdx.x; kk < NKK; kk += blockDim.x){
        float4 kvc = g_kvc[m*NKK + kk];
        float2 S = g_S[m*NKK + kk];
        acc += kvc.w*(S.x*S.x + S.y*S.y);
    }
    acc = waveReduce(acc);
    __shared__ float red[4];
    int lane = threadIdx.x & 63, w = threadIdx.x >> 6;
    if (!lane) red[w] = acc;
    __syncthreads();
    if (threadIdx.x == 0){
        float yew = red[0]+red[1]+red[2]+red[3];
        float D = g_D;
        float yslab = KE_C*(TWO_PI_C/g_vbox[m])*D*D;
        g_yrecip[m] = KE_C*(yew - SELF_C*g_self[m]) + yslab;
    }
}

// dense pair sweep over the filtered records
template<int PASS>
__global__ void k_pairs_c(){
    __shared__ float sreal[NMOL], sborn[NMOL];
    if (PASS == 0){
        if (threadIdx.x < NMOL){ sreal[threadIdx.x] = 0.f; sborn[threadIdx.x] = 0.f; }
        __syncthreads();
    }
    int nrec = g_nrec; if (nrec > CAPREC) nrec = CAPREC;
    int stride = gridDim.x*blockDim.x;
    for (int r = blockIdx.x*blockDim.x + threadIdx.x; r < nrec; r += stride){
        float4 A = g_recA[r];
        float4 B = g_recB[r];
        unsigned ij = __float_as_uint(A.x);
        int i = ij & 0xffff, j = ij >> 16;
        float rx = A.y, ry = A.z, rz = A.w;
        float r0 = B.x, nij = B.y, qq = B.z, d2 = B.w;
        float d = sqrtf(d2);
        float inv_d = 1.f/d;
        float Bc = fabsf(qq)*powf(r0, nij - 1.f)/nij;
        float er = erfcf(SQRT_ALPHA_C*d);
        float expt = expf(-ALPHA_C*d2);
        float dmn = powf(d, -nij);                        // d^-n
        float fp = -ACONST_C*expt*inv_d - er*inv_d*inv_d; // f'(d)
        float Up = 0.5f*KE_C*(qq*fp - Bc*nij*dmn*inv_d);  // U'(d)
        if (PASS == 0){
            float pot  = qq*(er*inv_d - g_FRC);
            float born = Bc*(dmn - powf(CUTOFF_C, -nij));
            int mm = i >> LOG2PERM;
            atomicAdd(&sreal[mm], pot);
            atomicAdd(&sborn[mm], born);
            float sc = Up*inv_d;
            float gx = sc*rx, gy = sc*ry, gz = sc*rz;
            atomicAdd(&g_G[j].x,  gx); atomicAdd(&g_G[j].y,  gy); atomicAdd(&g_G[j].z,  gz);
            atomicAdd(&g_G[i].x, -gx); atomicAdd(&g_G[i].y, -gy); atomicAdd(&g_G[i].z, -gz);
        } else {
            float fpp = ACONST_C*expt*(2.f*ALPHA_C + 2.f*inv_d*inv_d) + 2.f*er*inv_d*inv_d*inv_d;
            float Upp = 0.5f*KE_C*(qq*fpp + Bc*nij*(nij+1.f)*dmn*inv_d*inv_d);
            float4 vi = g_V[i], vj = g_V[j];
            float dvx = vj.x - vi.x, dvy = vj.y - vi.y, dvz = vj.z - vi.z;
            float ddot = (rx*dvx + ry*dvy + rz*dvz)*inv_d;
            float ui = Up*inv_d;
            float c1 = (Upp - ui)*ddot*inv_d;
            float gx = c1*rx + ui*dvx;
            float gy = c1*ry + ui*dvy;
            float gz = c1*rz + ui*dvz;
            atomicAdd(&g_HV[j].x,  gx); atomicAdd(&g_HV[j].y,  gy); atomicAdd(&g_HV[j].z,  gz);
            atomicAdd(&g_HV[i].x, -gx); atomicAdd(&g_HV[i].y, -gy); atomicAdd(&g_HV[i].z, -gz);
        }
    }
    if (PASS == 0){
        __syncthreads();
        if (threadIdx.x < NMOL){
            atomicAdd(&g_yreal[threadIdx.x], sreal[threadIdx.x]);
            atomicAdd(&g_yborn[threadIdx.x], sborn[threadIdx.x]);
        }
    }
}

template<int PASS>
__global__ void k_recip_grad(){
    int n = blockIdx.x*blockDim.x + threadIdx.x;
    int m = n >> LOG2PERM;
    float4 x4 = g_X[n];
    float4 v4 = make_float4(0.f,0.f,0.f,0.f);
    if (PASS) v4 = g_V[n];
    float ax = 0.f, ay = 0.f, az = 0.f;
    const float4* kvb = g_kvc + m*NKK;
    const float2* Sb  = g_S   + m*NKK;
    const float2* Sdb = g_Sd  + m*NKK;
    for (int kk = 0; kk < NKK; ++kk){
        float4 kvc = kvb[kk];
        if (kvc.w == 0.f) continue;
        float th = kvc.x*x4.x + kvc.y*x4.y + kvc.z*x4.z;
        float s, c;
        sincosf(th, &s, &c);
        float2 S = Sb[kk];
        float t;
        if (PASS == 0){
            t = kvc.w*(S.y*c - S.x*s);
        } else {
            float2 Sd = Sdb[kk];
            float thd = kvc.x*v4.x + kvc.y*v4.y + kvc.z*v4.z;
            t = kvc.w*(Sd.y*c - Sd.x*s - (S.y*s + S.x*c)*thd);
        }
        ax += t*kvc.x; ay += t*kvc.y; az += t*kvc.z;
    }
    float sc = 2.f*KE_C*x4.w;
    float slab = 2.f*KE_C*g_C2*x4.w*(PASS ? g_Dd : g_D);
    float4* T = PASS ? g_HV : g_G;
    float4 t0 = T[n];
    t0.x += sc*ax;
    t0.y += sc*ay;
    t0.z += sc*az + slab;
    T[n] = t0;
}

__global__ void k_reduce_F(const int* is_film){
    int m = blockIdx.x;
    float fx = 0.f, fy = 0.f, fz = 0.f;
    for (int a = threadIdx.x; a < PERM; a += blockDim.x){
        int n = (m << LOG2PERM) + a;
        float film = (float)is_film[n];
        float4 g = g_G[n];
        fx -= film*g.x; fy -= film*g.y; fz -= film*g.z;
    }
    fx = waveReduce(fx); fy = waveReduce(fy); fz = waveReduce(fz);
    __shared__ float red[12];
    int lane = threadIdx.x & 63, w = threadIdx.x >> 6;
    if (!lane){ red[w] = fx; red[4+w] = fy; red[8+w] = fz; }
    __syncthreads();
    if (threadIdx.x == 0){
        float FX = red[0]+red[1]+red[2]+red[3];
        float FY = red[4]+red[5]+red[6]+red[7];
        float FZ = red[8]+red[9]+red[10]+red[11];
        g_Fm[m][0] = FX; g_Fm[m][1] = FY; g_Fm[m][2] = FZ;
        g_norm2[m] = FX*FX + FY*FY + FZ*FZ;
    }
}

__global__ void k_setV(const int* is_film){
    int n = blockIdx.x*blockDim.x + threadIdx.x;
    int m = n >> LOG2PERM;
    float film = (float)is_film[n];
    float vx = film*g_Fm[m][0], vy = film*g_Fm[m][1], vz = film*g_Fm[m][2];
    g_V[n] = make_float4(vx, vy, vz, film);
    float contrib = waveReduce(g_X[n].w * vz);
    __shared__ float red[4];
    int lane = threadIdx.x & 63, w = threadIdx.x >> 6;
    if (!lane) red[w] = contrib;
    __syncthreads();
    if (threadIdx.x == 0) atomicAdd(&g_Dd, red[0]+red[1]+red[2]+red[3]);
}

__global__ void k_final(const int* is_film, float* out){
    int m = blockIdx.x;
    float ax = 0.f, ay = 0.f, az = 0.f;
    for (int a = threadIdx.x; a < PERM; a += blockDim.x){
        int n = (m << LOG2PERM) + a;
        float film = (float)is_film[n];
        float4 hv = g_HV[n];
        ax += film*hv.x; ay += film*hv.y; az += film*hv.z;
    }
    ax = waveReduce(ax); ay = waveReduce(ay); az = waveReduce(az);
    __shared__ float red[12];
    int lane = threadIdx.x & 63, w = threadIdx.x >> 6;
    if (!lane){ red[w] = ax; red[4+w] = ay; red[8+w] = az; }
    __syncthreads();
    if (threadIdx.x == 0){
        float AX = red[0]+red[1]+red[2]+red[3];
        float AY = red[4]+red[5]+red[6]+red[7];
        float AZ = red[8]+red[9]+red[10]+red[11];
        out[32 + 3*m + 0] = -2.f*AX;
        out[32 + 3*m + 1] = -2.f*AY;
        out[32 + 3*m + 2] = -2.f*AZ;
        float yr = 0.5f*KE_C*g_yreal[m];
        float yb = 0.5f*KE_C*g_yborn[m];
        float yc = yr + g_yrecip[m];
        out[0  + m] = yc + yb;
        out[8  + m] = yc;
        out[16 + m] = yb;
        out[24 + m] = g_norm2[m];
    }
}

extern "C" void kernel_launch(void* const* d_in, const int* in_sizes, int n_in,
                              void* d_out, int out_size, void* d_ws, size_t ws_size,
                              hipStream_t stream){
    const float* q       = (const float*)d_in[0];
    const float* R       = (const float*)d_in[1];
    const float* shift   = (const float*)d_in[2];
    const float* cell    = (const float*)d_in[3];
    const float* offsets = (const float*)d_in[4];
    const float* r0_ij   = (const float*)d_in[5];
    const float* n_ij    = (const float*)d_in[6];
    const int*   idx_i   = (const int*)d_in[7];
    const int*   idx_j   = (const int*)d_in[8];
    const int*   is_film = (const int*)d_in[10];
    float* out = (float*)d_out;

    k_zero<<<dim3(128), dim3(256), 0, stream>>>();
    k_prep<<<dim3(1), dim3(64), 0, stream>>>(cell);
    k_kvec<<<dim3((NMOL*NKK + 255)/256), dim3(256), 0, stream>>>();
    k_shift<<<dim3(NATOM/256), dim3(256), 0, stream>>>(q, R, shift, is_film);
    k_filter<<<dim3(512), dim3(256), 0, stream>>>(idx_i, idx_j, offsets, r0_ij, n_ij);
    k_sfac<0><<<dim3(NMOL*NKK), dim3(256), 0, stream>>>();
    k_recip_energy<<<dim3(NMOL), dim3(256), 0, stream>>>();
    k_pairs_c<0><<<dim3(512), dim3(256), 0, stream>>>();
    k_recip_grad<0><<<dim3(NATOM/256), dim3(256), 0, stream>>>();
    k_reduce_F<<<dim3(NMOL), dim3(256), 0, stream>>>(is_film);
    k_setV<<<dim3(NATOM/256), dim3(256), 0, stream>>>(is_film);
    k_sfac<1><<<dim3(NMOL*NKK), dim3(256), 0, stream>>>();
    k_pairs_c<1><<<dim3(512), dim3(256), 0, stream>>>();
    k_recip_grad<1><<<dim3(NATOM/256), dim3(256), 0, stream>>>();
    k_final<<<dim3(NMOL), dim3(256), 0, stream>>>(is_film, out);
}

// Round 3
// 284.639 us; speedup vs baseline: 2.4773x; 1.9011x over previous
//
#include <hip/hip_runtime.h>
#include <math.h>

#define NATOM 32768
#define NMOL 8
#define PERM 4096
#define LOG2PERM 12
#define NPAIR 2097152
#define NKK 625           // 25x25 k-grid, invalid entries get coef=0
#define CAPREC 524288     // capacity for filtered pairs (~210k expected)

#define KE_C 14.3996f
#define ALPHA_C 0.3f
#define CUTOFF_C 6.0f
#define SQRT_ALPHA_C 0.5477225575051661f   // sqrt(0.3)
#define ACONST_C 0.6180387232371366f       // 2*sqrt(alpha/pi)
#define SELF_C 0.3090193616185683f         // sqrt(alpha/pi)
#define TWO_PI_C 6.283185307179586f
#define LN_CUTOFF_C 1.791759469228055f     // ln(6)

// persistent device state (zeroed per launch as needed)
__device__ float4 g_X[NATOM];      // x,y,z,q
__device__ float4 g_V[NATOM];      // tangent direction (film*F), w=film
__device__ float4 g_G[NATOM];      // dE/dX
__device__ float4 g_HV[NATOM];     // H*V
__device__ float4 g_kvc[NMOL*NKK]; // kvx,kvy,kvz,coef
__device__ float2 g_S[NMOL*NKK];   // S_re,S_im
__device__ float2 g_Sd[NMOL*NKK];  // Sdot_re,Sdot_im
__device__ float4 g_recA[CAPREC];  // packed ij, rx, ry, rz
__device__ float4 g_recB[CAPREC];  // r0, n, qq, d2
__device__ int   g_nrec;
__device__ float g_recipM[NMOL][9];
__device__ float g_vbox[NMOL];
__device__ float g_self[NMOL];
__device__ float g_yreal[NMOL];
__device__ float g_yborn[NMOL];
__device__ float g_yrecip[NMOL];
__device__ float g_Fm[NMOL][3];
__device__ float g_norm2[NMOL];
__device__ float g_D, g_Dd, g_C2, g_FRC;

__device__ __forceinline__ float waveReduce(float v){
#pragma unroll
    for (int off = 32; off > 0; off >>= 1) v += __shfl_down(v, off, 64);
    return v;
}

__global__ void k_zero(){
    int id = blockIdx.x*blockDim.x + threadIdx.x;
    if (id < NATOM){
        g_G[id]  = make_float4(0.f,0.f,0.f,0.f);
        g_HV[id] = make_float4(0.f,0.f,0.f,0.f);
    }
    if (id < NMOL*NKK){
        g_S[id]  = make_float2(0.f,0.f);
        g_Sd[id] = make_float2(0.f,0.f);
    }
    if (id < NMOL){
        g_self[id] = 0.f; g_yreal[id] = 0.f; g_yborn[id] = 0.f;
    }
    if (id == 0){ g_D = 0.f; g_Dd = 0.f; g_nrec = 0; }
}

__global__ void k_prep(const float* cell){
    int m = threadIdx.x;
    if (m < NMOL){
        const float* c = cell + 9*m;
        float a=c[0],b=c[1],cc=c[2],d=c[3],e=c[4],f=c[5],g=c[6],h=c[7],i=c[8];
        float det = a*(e*i - f*h) - b*(d*i - f*g) + cc*(d*h - e*g);
        float inv = 1.f/det;
        float i00=(e*i-f*h)*inv,  i01=(cc*h-b*i)*inv, i02=(b*f-cc*e)*inv;
        float i10=(f*g-d*i)*inv,  i11=(a*i-cc*g)*inv, i12=(cc*d-a*f)*inv;
        float i20=(d*h-e*g)*inv,  i21=(b*g-a*h)*inv,  i22=(a*e-b*d)*inv;
        // recipM[d][e] = 2*pi*inv[e][d]  (swapaxes of inverse)
        g_recipM[m][0]=TWO_PI_C*i00; g_recipM[m][1]=TWO_PI_C*i10; g_recipM[m][2]=TWO_PI_C*i20;
        g_recipM[m][3]=TWO_PI_C*i01; g_recipM[m][4]=TWO_PI_C*i11; g_recipM[m][5]=TWO_PI_C*i21;
        g_recipM[m][6]=TWO_PI_C*i02; g_recipM[m][7]=TWO_PI_C*i12; g_recipM[m][8]=TWO_PI_C*i22;
        g_vbox[m] = fabsf(det);
    }
    __syncthreads();
    if (threadIdx.x == 0){
        float c2 = 0.f;
        for (int mm = 0; mm < NMOL; ++mm) c2 += TWO_PI_C/g_vbox[mm];
        g_C2 = c2;
        g_FRC = (float)(erfc(sqrt(0.3)*6.0)/6.0);
    }
}

__global__ void k_kvec(){
    int id = blockIdx.x*blockDim.x + threadIdx.x;
    if (id >= NMOL*NKK) return;
    int m = id / NKK;
    int kk = id % NKK;
    int ix = kk / 25, iy = kk % 25;
    float kx = (ix <= 12) ? (float)ix : (float)(-(ix-12));
    float ky = (iy <= 12) ? (float)iy : (float)(-(iy-12));
    float nrm = kx*kx + ky*ky;
    float kvx = kx*g_recipM[m][0] + ky*g_recipM[m][3];
    float kvy = kx*g_recipM[m][1] + ky*g_recipM[m][4];
    float kvz = kx*g_recipM[m][2] + ky*g_recipM[m][5];
    float coef = 0.f;
    if (nrm != 0.f && nrm <= 146.f){
        float ksq = kvx*kvx + kvy*kvy + kvz*kvz;
        coef = (TWO_PI_C/g_vbox[m]) * expf(-0.25f*ksq/ALPHA_C) / ksq;
    }
    g_kvc[id] = make_float4(kvx, kvy, kvz, coef);
}

__global__ void k_shift(const float* q, const float* R, const float* shift, const int* is_film){
    int n = blockIdx.x*blockDim.x + threadIdx.x;
    int m = n >> LOG2PERM;
    int film = is_film[n];
    float qn = q[n];
    float x = R[3*n+0], y = R[3*n+1], z = R[3*n+2];
    if (film){ x += shift[3*m+0]; y += shift[3*m+1]; z += shift[3*m+2]; }
    g_X[n] = make_float4(x, y, z, qn);
    float vD = waveReduce(qn*z);
    float vS = waveReduce(qn*qn);
    __shared__ float red[8];
    int lane = threadIdx.x & 63, w = threadIdx.x >> 6;
    if (!lane){ red[w] = vD; red[4+w] = vS; }
    __syncthreads();
    if (threadIdx.x == 0){
        atomicAdd(&g_D, red[0]+red[1]+red[2]+red[3]);
        atomicAdd(&g_self[m], red[4]+red[5]+red[6]+red[7]);
    }
}

// filter the 2M pairs down to the ~10% inside the cutoff; store precomputed
// displacement + pair params so the pair kernels do no position gathers.
__global__ void k_filter(const int* idx_i, const int* idx_j, const float* offsets,
                         const float* r0_ij, const float* n_ij){
    __shared__ int s_red[4];
    __shared__ int s_cur;
    int tid = threadIdx.x;
    int p0 = blockIdx.x * 4096;
    int cnt = 0;
    for (int it = 0; it < 16; ++it){
        int p = p0 + it*256 + tid;
        int i = idx_i[p], j = idx_j[p];
        float4 xi = g_X[i], xj = g_X[j];
        float rx = xj.x - xi.x + offsets[3*p+0];
        float ry = xj.y - xi.y + offsets[3*p+1];
        float rz = xj.z - xi.z + offsets[3*p+2];
        float d2 = rx*rx + ry*ry + rz*rz;
        if (d2 < CUTOFF_C*CUTOFF_C) ++cnt;
    }
#pragma unroll
    for (int off = 32; off > 0; off >>= 1) cnt += __shfl_down(cnt, off, 64);
    int lane = tid & 63, w = tid >> 6;
    if (!lane) s_red[w] = cnt;
    __syncthreads();
    if (tid == 0) s_cur = atomicAdd(&g_nrec, s_red[0]+s_red[1]+s_red[2]+s_red[3]);
    __syncthreads();
    for (int it = 0; it < 16; ++it){
        int p = p0 + it*256 + tid;
        int i = idx_i[p], j = idx_j[p];
        float4 xi = g_X[i], xj = g_X[j];
        float rx = xj.x - xi.x + offsets[3*p+0];
        float ry = xj.y - xi.y + offsets[3*p+1];
        float rz = xj.z - xi.z + offsets[3*p+2];
        float d2 = rx*rx + ry*ry + rz*rz;
        if (d2 < CUTOFF_C*CUTOFF_C){
            int slot = atomicAdd(&s_cur, 1);
            if (slot < CAPREC){
                g_recA[slot] = make_float4(__uint_as_float((unsigned)i | ((unsigned)j << 16)), rx, ry, rz);
                g_recB[slot] = make_float4(r0_ij[p], n_ij[p], xi.w*xj.w, d2);
            }
        }
    }
}

template<int DOT>
__global__ void k_sfac(){
    int bid = blockIdx.x;
    int m = bid / NKK;
    float4 kvc = g_kvc[bid];
    if (kvc.w == 0.f) return;   // uniform per block
    float sre = 0.f, sim = 0.f;
    for (int a = threadIdx.x; a < PERM; a += blockDim.x){
        int n = (m << LOG2PERM) + a;
        float4 x = g_X[n];
        float th = kvc.x*x.x + kvc.y*x.y + kvc.z*x.z;
        float s, c;
        __sincosf(th, &s, &c);
        if (DOT){
            float4 v = g_V[n];
            float thd = kvc.x*v.x + kvc.y*v.y + kvc.z*v.z;
            sre -= x.w*s*thd;
            sim += x.w*c*thd;
        } else {
            sre += x.w*c;
            sim += x.w*s;
        }
    }
    sre = waveReduce(sre); sim = waveReduce(sim);
    __shared__ float red[8];
    int lane = threadIdx.x & 63, w = threadIdx.x >> 6;
    if (!lane){ red[w] = sre; red[4+w] = sim; }
    __syncthreads();
    if (threadIdx.x == 0){
        float2 o = make_float2(red[0]+red[1]+red[2]+red[3], red[4]+red[5]+red[6]+red[7]);
        if (DOT) g_Sd[bid] = o; else g_S[bid] = o;
    }
}

__global__ void k_recip_energy(){
    int m = blockIdx.x;
    float acc = 0.f;
    for (int kk = threadIdx.x; kk < NKK; kk += blockDim.x){
        float4 kvc = g_kvc[m*NKK + kk];
        float2 S = g_S[m*NKK + kk];
        acc += kvc.w*(S.x*S.x + S.y*S.y);
    }
    acc = waveReduce(acc);
    __shared__ float red[4];
    int lane = threadIdx.x & 63, w = threadIdx.x >> 6;
    if (!lane) red[w] = acc;
    __syncthreads();
    if (threadIdx.x == 0){
        float yew = red[0]+red[1]+red[2]+red[3];
        float D = g_D;
        float yslab = KE_C*(TWO_PI_C/g_vbox[m])*D*D;
        g_yrecip[m] = KE_C*(yew - SELF_C*g_self[m]) + yslab;
    }
}

// dense pair sweep over the filtered records
template<int PASS>
__global__ void k_pairs_c(){
    __shared__ float sreal[NMOL], sborn[NMOL];
    if (PASS == 0){
        if (threadIdx.x < NMOL){ sreal[threadIdx.x] = 0.f; sborn[threadIdx.x] = 0.f; }
        __syncthreads();
    }
    int nrec = g_nrec; if (nrec > CAPREC) nrec = CAPREC;
    int stride = gridDim.x*blockDim.x;
    for (int r = blockIdx.x*blockDim.x + threadIdx.x; r < nrec; r += stride){
        float4 A = g_recA[r];
        float4 B = g_recB[r];
        unsigned ij = __float_as_uint(A.x);
        int i = ij & 0xffff, j = ij >> 16;
        float rx = A.y, ry = A.z, rz = A.w;
        float r0 = B.x, nij = B.y, qq = B.z, d2 = B.w;
        float d = sqrtf(d2);
        float inv_d = 1.f/d;
        float Bc = fabsf(qq)*__expf((nij - 1.f)*__logf(r0))/nij;
        float er = erfcf(SQRT_ALPHA_C*d);
        float expt = __expf(-ALPHA_C*d2);
        float dmn = __expf(-nij*__logf(d));               // d^-n
        float fp = -ACONST_C*expt*inv_d - er*inv_d*inv_d; // f'(d)
        float Up = 0.5f*KE_C*(qq*fp - Bc*nij*dmn*inv_d);  // U'(d)
        if (PASS == 0){
            float pot  = qq*(er*inv_d - g_FRC);
            float born = Bc*(dmn - __expf(-nij*LN_CUTOFF_C));
            int mm = i >> LOG2PERM;
            atomicAdd(&sreal[mm], pot);
            atomicAdd(&sborn[mm], born);
            float sc = Up*inv_d;
            float gx = sc*rx, gy = sc*ry, gz = sc*rz;
            atomicAdd(&g_G[j].x,  gx); atomicAdd(&g_G[j].y,  gy); atomicAdd(&g_G[j].z,  gz);
            atomicAdd(&g_G[i].x, -gx); atomicAdd(&g_G[i].y, -gy); atomicAdd(&g_G[i].z, -gz);
        } else {
            float fpp = ACONST_C*expt*(2.f*ALPHA_C + 2.f*inv_d*inv_d) + 2.f*er*inv_d*inv_d*inv_d;
            float Upp = 0.5f*KE_C*(qq*fpp + Bc*nij*(nij+1.f)*dmn*inv_d*inv_d);
            float4 vi = g_V[i], vj = g_V[j];
            float dvx = vj.x - vi.x, dvy = vj.y - vi.y, dvz = vj.z - vi.z;
            float ddot = (rx*dvx + ry*dvy + rz*dvz)*inv_d;
            float ui = Up*inv_d;
            float c1 = (Upp - ui)*ddot*inv_d;
            float gx = c1*rx + ui*dvx;
            float gy = c1*ry + ui*dvy;
            float gz = c1*rz + ui*dvz;
            atomicAdd(&g_HV[j].x,  gx); atomicAdd(&g_HV[j].y,  gy); atomicAdd(&g_HV[j].z,  gz);
            atomicAdd(&g_HV[i].x, -gx); atomicAdd(&g_HV[i].y, -gy); atomicAdd(&g_HV[i].z, -gz);
        }
    }
    if (PASS == 0){
        __syncthreads();
        if (threadIdx.x < NMOL){
            atomicAdd(&g_yreal[threadIdx.x], sreal[threadIdx.x]);
            atomicAdd(&g_yborn[threadIdx.x], sborn[threadIdx.x]);
        }
    }
}

// reciprocal-space gradient via phasor recurrence:
// theta_nk = kx*(b1.x_n) + ky*(b2.x_n); grad accumulates A1=sum t*kx, A2=sum t*ky
// then g = A1*b1 + A2*b2. 4 sincosf per atom total, no per-entry trig.
#define RG_BLOCK 64
template<int PASS>
__global__ void k_recip_grad(){
    __shared__ float2 s_u[NKK];   // coef * S,  reordered to a=(kx+12)*25+(ky+12)
    __shared__ float2 s_v[NKK];   // coef * Sd  (PASS1 only)
    __shared__ float  s_b[6];     // b1 (row0), b2 (row1) of recipM
    int tid = threadIdx.x;
    int n = blockIdx.x*RG_BLOCK + tid;
    int m = n >> LOG2PERM;
    if (tid < 6) s_b[tid] = g_recipM[m][tid];
    for (int a = tid; a < NKK; a += RG_BLOCK){
        int kx = a/25 - 12, ky = a%25 - 12;
        int ixo = (kx >= 0) ? kx : 12 - kx;
        int iyo = (ky >= 0) ? ky : 12 - ky;
        int src = m*NKK + ixo*25 + iyo;
        float c = g_kvc[src].w;
        float2 S = g_S[src];
        s_u[a] = make_float2(c*S.x, c*S.y);
        if (PASS){
            float2 Sd = g_Sd[src];
            s_v[a] = make_float2(c*Sd.x, c*Sd.y);
        }
    }
    __syncthreads();
    float4 x4 = g_X[n];
    float b1x=s_b[0], b1y=s_b[1], b1z=s_b[2];
    float b2x=s_b[3], b2y=s_b[4], b2z=s_b[5];
    float th1 = b1x*x4.x + b1y*x4.y + b1z*x4.z;
    float th2 = b2x*x4.x + b2y*x4.y + b2z*x4.z;
    float E1s, E1c, E2s, E2c, Ps, Pc, Q0s, Q0c;
    sincosf(th1, &E1s, &E1c);
    sincosf(th2, &E2s, &E2c);
    sincosf(-12.f*th1, &Ps, &Pc);
    sincosf(-12.f*th2, &Q0s, &Q0c);
    float phi1 = 0.f, phi2 = 0.f;
    if (PASS){
        float4 v4 = g_V[n];
        phi1 = b1x*v4.x + b1y*v4.y + b1z*v4.z;
        phi2 = b2x*v4.x + b2y*v4.y + b2z*v4.z;
    }
    float A1 = 0.f, A2 = 0.f;
    int a = 0;
    for (int kxi = 0; kxi < 25; ++kxi){
        float kx = (float)(kxi - 12);
        float pc = Pc*Q0c - Ps*Q0s;
        float ps = Pc*Q0s + Ps*Q0c;
        for (int kyi = 0; kyi < 25; ++kyi, ++a){
            float ky = (float)(kyi - 12);
            float2 u = s_u[a];
            float t;
            if (PASS == 0){
                t = u.y*pc - u.x*ps;
            } else {
                float2 v = s_v[a];
                float thd = kx*phi1 + ky*phi2;
                t = v.y*pc - v.x*ps - (u.y*ps + u.x*pc)*thd;
            }
            A1 += t*kx; A2 += t*ky;
            float npc = pc*E2c - ps*E2s;
            float nps = pc*E2s + ps*E2c;
            pc = npc; ps = nps;
        }
        float nPc = Pc*E1c - Ps*E1s;
        float nPs = Pc*E1s + Ps*E1c;
        Pc = nPc; Ps = nPs;
    }
    float gx = A1*b1x + A2*b2x;
    float gy = A1*b1y + A2*b2y;
    float gz = A1*b1z + A2*b2z;
    float sc = 2.f*KE_C*x4.w;
    float slab = 2.f*KE_C*g_C2*x4.w*(PASS ? g_Dd : g_D);
    float4* T = PASS ? g_HV : g_G;
    float4 t0 = T[n];
    t0.x += sc*gx;
    t0.y += sc*gy;
    t0.z += sc*gz + slab;
    T[n] = t0;
}

__global__ void k_reduce_F(const int* is_film){
    int m = blockIdx.x;
    float fx = 0.f, fy = 0.f, fz = 0.f;
    for (int a = threadIdx.x; a < PERM; a += blockDim.x){
        int n = (m << LOG2PERM) + a;
        float film = (float)is_film[n];
        float4 g = g_G[n];
        fx -= film*g.x; fy -= film*g.y; fz -= film*g.z;
    }
    fx = waveReduce(fx); fy = waveReduce(fy); fz = waveReduce(fz);
    __shared__ float red[12];
    int lane = threadIdx.x & 63, w = threadIdx.x >> 6;
    if (!lane){ red[w] = fx; red[4+w] = fy; red[8+w] = fz; }
    __syncthreads();
    if (threadIdx.x == 0){
        float FX = red[0]+red[1]+red[2]+red[3];
        float FY = red[4]+red[5]+red[6]+red[7];
        float FZ = red[8]+red[9]+red[10]+red[11];
        g_Fm[m][0] = FX; g_Fm[m][1] = FY; g_Fm[m][2] = FZ;
        g_norm2[m] = FX*FX + FY*FY + FZ*FZ;
    }
}

__global__ void k_setV(const int* is_film){
    int n = blockIdx.x*blockDim.x + threadIdx.x;
    int m = n >> LOG2PERM;
    float film = (float)is_film[n];
    float vx = film*g_Fm[m][0], vy = film*g_Fm[m][1], vz = film*g_Fm[m][2];
    g_V[n] = make_float4(vx, vy, vz, film);
    float contrib = waveReduce(g_X[n].w * vz);
    __shared__ float red[4];
    int lane = threadIdx.x & 63, w = threadIdx.x >> 6;
    if (!lane) red[w] = contrib;
    __syncthreads();
    if (threadIdx.x == 0) atomicAdd(&g_Dd, red[0]+red[1]+red[2]+red[3]);
}

__global__ void k_final(const int* is_film, float* out){
    int m = blockIdx.x;
    float ax = 0.f, ay = 0.f, az = 0.f;
    for (int a = threadIdx.x; a < PERM; a += blockDim.x){
        int n = (m << LOG2PERM) + a;
        float film = (float)is_film[n];
        float4 hv = g_HV[n];
        ax += film*hv.x; ay += film*hv.y; az += film*hv.z;
    }
    ax = waveReduce(ax); ay = waveReduce(ay); az = waveReduce(az);
    __shared__ float red[12];
    int lane = threadIdx.x & 63, w = threadIdx.x >> 6;
    if (!lane){ red[w] = ax; red[4+w] = ay; red[8+w] = az; }
    __syncthreads();
    if (threadIdx.x == 0){
        float AX = red[0]+red[1]+red[2]+red[3];
        float AY = red[4]+red[5]+red[6]+red[7];
        float AZ = red[8]+red[9]+red[10]+red[11];
        out[32 + 3*m + 0] = -2.f*AX;
        out[32 + 3*m + 1] = -2.f*AY;
        out[32 + 3*m + 2] = -2.f*AZ;
        float yr = 0.5f*KE_C*g_yreal[m];
        float yb = 0.5f*KE_C*g_yborn[m];
        float yc = yr + g_yrecip[m];
        out[0  + m] = yc + yb;
        out[8  + m] = yc;
        out[16 + m] = yb;
        out[24 + m] = g_norm2[m];
    }
}

extern "C" void kernel_launch(void* const* d_in, const int* in_sizes, int n_in,
                              void* d_out, int out_size, void* d_ws, size_t ws_size,
                              hipStream_t stream){
    const float* q       = (const float*)d_in[0];
    const float* R       = (const float*)d_in[1];
    const float* shift   = (const float*)d_in[2];
    const float* cell    = (const float*)d_in[3];
    const float* offsets = (const float*)d_in[4];
    const float* r0_ij   = (const float*)d_in[5];
    const float* n_ij    = (const float*)d_in[6];
    const int*   idx_i   = (const int*)d_in[7];
    const int*   idx_j   = (const int*)d_in[8];
    const int*   is_film = (const int*)d_in[10];
    float* out = (float*)d_out;

    k_zero<<<dim3(128), dim3(256), 0, stream>>>();
    k_prep<<<dim3(1), dim3(64), 0, stream>>>(cell);
    k_kvec<<<dim3((NMOL*NKK + 255)/256), dim3(256), 0, stream>>>();
    k_shift<<<dim3(NATOM/256), dim3(256), 0, stream>>>(q, R, shift, is_film);
    k_filter<<<dim3(512), dim3(256), 0, stream>>>(idx_i, idx_j, offsets, r0_ij, n_ij);
    k_sfac<0><<<dim3(NMOL*NKK), dim3(256), 0, stream>>>();
    k_recip_energy<<<dim3(NMOL), dim3(256), 0, stream>>>();
    k_pairs_c<0><<<dim3(512), dim3(256), 0, stream>>>();
    k_recip_grad<0><<<dim3(NATOM/RG_BLOCK), dim3(RG_BLOCK), 0, stream>>>();
    k_reduce_F<<<dim3(NMOL), dim3(256), 0, stream>>>(is_film);
    k_setV<<<dim3(NATOM/256), dim3(256), 0, stream>>>(is_film);
    k_sfac<1><<<dim3(NMOL*NKK), dim3(256), 0, stream>>>();
    k_pairs_c<1><<<dim3(512), dim3(256), 0, stream>>>();
    k_recip_grad<1><<<dim3(NATOM/RG_BLOCK), dim3(RG_BLOCK), 0, stream>>>();
    k_final<<<dim3(NMOL), dim3(256), 0, stream>>>(is_film, out);
}